// Round 5
// baseline (3424.610 us; speedup 1.0000x reference)
//
#include <hip/hip_runtime.h>
#include <stdint.h>

typedef uint16_t u16;
typedef short short8 __attribute__((ext_vector_type(8)));
typedef float f32x4 __attribute__((ext_vector_type(4)));

__device__ __forceinline__ u16 f2bf(float f){
  uint32_t u = __float_as_uint(f);
  u += 0x7fff + ((u >> 16) & 1);   // RNE
  return (u16)(u >> 16);
}

__device__ __forceinline__ void gload_lds16(const u16* g, const char* l){
  __builtin_amdgcn_global_load_lds((const __attribute__((address_space(1))) void*)g,
                                   (__attribute__((address_space(3))) void*)l,
                                   16, 0, 0);
}

// ---- prep: fp32 -> bf16 cast (vectorized, 8 elems/thread/iter) ----
__global__ void cast_bf16_kernel(const float* __restrict__ src, u16* __restrict__ dst, long n8){
  long i = (long)blockIdx.x * blockDim.x + threadIdx.x;
  long stride = (long)gridDim.x * blockDim.x;
  for (; i < n8; i += stride){
    float4 a = *(const float4*)(src + i*8);
    float4 b = *(const float4*)(src + i*8 + 4);
    u16 r[8] = {f2bf(a.x), f2bf(a.y), f2bf(a.z), f2bf(a.w),
                f2bf(b.x), f2bf(b.y), f2bf(b.z), f2bf(b.w)};
    *(uint4*)(dst + i*8) = *(const uint4*)r;
  }
}

// ---- prep: L = tril(pre) cast to bf16 ; layout (n,u,v) 8x512x512 ----
__global__ void mask_cast_L_kernel(const float* __restrict__ pre, u16* __restrict__ L){
  long i = (long)blockIdx.x * blockDim.x + threadIdx.x;  // chunk of 8 along v
  if (i >= 8L*512*64) return;
  int v0 = (int)(i & 63) * 8;
  int u  = (int)((i >> 6) & 511);
  float4 a = *(const float4*)(pre + i*8);
  float4 b = *(const float4*)(pre + i*8 + 4);
  float vals[8] = {a.x,a.y,a.z,a.w,b.x,b.y,b.z,b.w};
  u16 r[8];
  #pragma unroll
  for (int j=0;j<8;j++) r[j] = f2bf((v0 + j <= u) ? vals[j] : 0.0f);
  *(uint4*)(L + i*8) = *(const uint4*)r;
}

// ---- deep-pipelined NT GEMM: C[M,N] = A(MxK,rm) * B(NxK,rm)^T ----
// 256x256 tile, BK=32, 8 waves (2Mx4N), each wave 128x64 = acc[8][4].
// 4 LDS K-tile buffers, prefetch 3 ahead, counted vmcnt(8), one barrier
// per K-tile, 32 MFMA per barrier, K-loop unrolled 4x (compile-time bufs).
// Swizzle g(r)=(r>>1)&3 on 16B chunks (conflict-free), both-sides.
// Wave-phase stagger: wm=1 waves run the two 16-MFMA half-bursts in opposite
// order so each SIMD (waves s, s+4 differ in wm) has one wave in ds_read
// while the other drains MFMA.
// SWZ: XCD-chunked blockIdx swizzle (nwg must be divisible by 8).
// EPI: 0 = store bf16; 1 = +bias[row] bf16; 2 = tril*scale bf16; 3 = +bias[col] fp32.
template<int EPI, bool SWZ>
__global__ __launch_bounds__(512, 1)
void gemm_nt2(const u16* __restrict__ A, const u16* __restrict__ B,
              void* __restrict__ Cv, int K, int lda, int ldb, int ldc,
              long asb, long asn, long bsb, long bsn, long csb, long csn,
              const float* __restrict__ bias, float scale)
{
  extern __shared__ __align__(16) char smem[];   // 4 * 32768 = 131072 B
  const int t = threadIdx.x;
  const int lane = t & 63;
  const int wave = t >> 6;          // 0..7
  const int wm = wave >> 2;         // 0..1
  const int wn = wave & 3;          // 0..3
  const int wodd = __builtin_amdgcn_readfirstlane(wm);  // scalar branch key
  const long zb = blockIdx.z >> 3, zn = blockIdx.z & 7;
  A += zb*asb + zn*asn;
  B += zb*bsb + zn*bsn;

  int bx = blockIdx.x, by = blockIdx.y;
  if constexpr (SWZ){
    int nbx = gridDim.x;
    int bid = bx + by * nbx;
    int chunk = (nbx * gridDim.y) >> 3;   // blocks per XCD
    int b2 = (bid & 7) * chunk + (bid >> 3);
    bx = b2 % nbx;  by = b2 / nbx;
  }
  const int row0 = by * 256, col0 = bx * 256;
  const int l15 = lane & 15, l4 = lane >> 4;

  // staging: thread t -> LDS slot t (16B), row = t>>2, chunk pos = t&3;
  // source chunk pre-swizzled: c_g = pos ^ g(row), g(r) = (r>>1)&3
  const int srow = t >> 2;                                // 0..127
  const int scol = (((t & 3) ^ ((srow >> 1) & 3)) * 8);   // elements
  const u16* gA = A + (long)(row0 + srow)*lda + scol;
  const u16* gB = B + (long)(col0 + srow)*ldb + scol;
  const long a128 = 128L*(long)lda, b128 = 128L*(long)ldb;
  const int ldst = t * 16;                                // byte slot

  // ds_read swizzled chunk: pos = l4 ^ g(row), row = (...)+l15 -> g from l15
  const int csw = (l4 ^ ((l15 >> 1) & 3)) * 16;
  const int raw = (wm*128 + l15)*64 + csw;          // A read base (bytes)
  const int rbw = 16384 + (wn*64 + l15)*64 + csw;   // B read base

  f32x4 acc[8][4];
  #pragma unroll
  for (int m=0;m<8;m++)
    #pragma unroll
    for (int n=0;n<4;n++) acc[m][n] = (f32x4){0.f,0.f,0.f,0.f};

  const int NT = K >> 5;   // NT % 4 == 0 here (K=512/4096)

#define STAGEM(PA, PB, BUF) \
  gload_lds16((PA),        smem + (BUF)*32768 +         ldst); \
  gload_lds16((PA) + a128, smem + (BUF)*32768 +  8192 + ldst); \
  gload_lds16((PB),        smem + (BUF)*32768 + 16384 + ldst); \
  gload_lds16((PB) + b128, smem + (BUF)*32768 + 24576 + ldst);

#define WAITB(VM) \
  asm volatile("s_waitcnt vmcnt(" VM ")" ::: "memory"); \
  __builtin_amdgcn_s_barrier(); \
  asm volatile("" ::: "memory");

#define HALF(BASE, MO) { \
  short8 afr[4]; \
  _Pragma("unroll") \
  for (int m=0;m<4;m++) afr[m] = *(const short8*)((BASE) + raw + (m+(MO))*1024); \
  __builtin_amdgcn_s_setprio(1); \
  _Pragma("unroll") \
  for (int m=0;m<4;m++) \
    _Pragma("unroll") \
    for (int n=0;n<4;n++) \
      acc[m+(MO)][n] = __builtin_amdgcn_mfma_f32_16x16x32_bf16(afr[m], bfr[n], acc[m+(MO)][n], 0,0,0); \
  __builtin_amdgcn_s_setprio(0); \
}

#define COMPUTE(BUF, ...) { \
  const char* base = smem + (BUF)*32768; \
  short8 bfr[4]; \
  _Pragma("unroll") \
  for (int n=0;n<4;n++) bfr[n] = *(const short8*)(base + rbw + n*1024); \
  __VA_ARGS__ \
  if (wodd){ HALF(base, 4) HALF(base, 0) } \
  else     { HALF(base, 0) HALF(base, 4) } \
}

  // prologue: 3 K-tiles in flight
  STAGEM(gA,      gB,      0);
  STAGEM(gA + 32, gB + 32, 1);
  STAGEM(gA + 64, gB + 64, 2);

  // main: tiles tk = tb..tb+3 (buffers 0..3), stage tk+3 (buffers 3,0,1,2)
  #pragma unroll 1
  for (int tb = 0; tb < NT - 4; tb += 4){
    const u16* pa = gA + (long)(tb + 3)*32;
    const u16* pb = gB + (long)(tb + 3)*32;
    WAITB("8"); COMPUTE(0, STAGEM(pa,      pb,      3));
    WAITB("8"); COMPUTE(1, STAGEM(pa + 32, pb + 32, 0));
    WAITB("8"); COMPUTE(2, STAGEM(pa + 64, pb + 64, 1));
    WAITB("8"); COMPUTE(3, STAGEM(pa + 96, pb + 96, 2));
  }
  // tail: tk = NT-4..NT-1 (buffers 0..3), one last stage
  {
    const u16* pa = gA + (long)(NT - 1)*32;
    const u16* pb = gB + (long)(NT - 1)*32;
    WAITB("8"); COMPUTE(0, STAGEM(pa, pb, 3));
    WAITB("8"); COMPUTE(1, );
    WAITB("4"); COMPUTE(2, );
    WAITB("0"); COMPUTE(3, );
  }
#undef STAGEM
#undef WAITB
#undef HALF
#undef COMPUTE

  // epilogue: C/D map col=lane&15, row=(lane>>4)*4+g  (HW-verified)
  if constexpr (EPI == 3){
    float* C = (float*)Cv;
    #pragma unroll
    for (int m=0;m<8;m++){
      int r0 = row0 + wm*128 + m*16 + l4*4;
      #pragma unroll
      for (int n=0;n<4;n++){
        int c = col0 + wn*64 + n*16 + l15;
        float bc = bias[c];
        #pragma unroll
        for (int g=0; g<4; g++)
          C[(long)(r0+g)*ldc + c] = acc[m][n][g] + bc;
      }
    }
  } else {
    u16* C = (u16*)Cv + zb*csb + zn*csn;
    #pragma unroll
    for (int m=0;m<8;m++){
      int r0 = row0 + wm*128 + m*16 + l4*4;
      #pragma unroll
      for (int n=0;n<4;n++){
        int c = col0 + wn*64 + n*16 + l15;
        #pragma unroll
        for (int g=0;g<4;g++){
          float v = acc[m][n][g];
          int r = r0 + g;
          if constexpr (EPI==1) v += bias[r];
          if constexpr (EPI==2) v = (c <= r) ? v*scale : 0.0f;
          C[(long)r*ldc + c] = f2bf(v);
        }
      }
    }
  }
}

// Workspace layout (bytes):
//   xb   @ 0          : 8192x4096 bf16
//   W1b  @ 67108864   : 4096x4096 bf16
//   W2b  @ 100663296  : 4096x4096 bf16
//   Lb   @ 134217728  : 8x512x512 bf16
//   Mb   @ 138412032  : 8x512x512 bf16
//   PtG  @ 142606336  : 4096x8192 bf16   PtG[c][r] = P_full[r][c]
//   MPt  @ 209715200  : 128x512x512 bf16 MPt[z][j][u] = MP[b,n,u,j]
//   Sb   @ 276824064  : 128x512x512 bf16
//   Ob   = MPt (reuse; MPt dead after S-gemm)

#define LDSB 131072

extern "C" void kernel_launch(void* const* d_in, const int* in_sizes, int n_in,
                              void* d_out, int out_size, void* d_ws, size_t ws_size,
                              hipStream_t stream)
{
  (void)in_sizes; (void)n_in; (void)out_size; (void)ws_size;
  const float* x   = (const float*)d_in[0];
  const float* W1  = (const float*)d_in[1];
  const float* b1  = (const float*)d_in[2];
  const float* pre = (const float*)d_in[3];
  const float* W2  = (const float*)d_in[4];
  const float* b2  = (const float*)d_in[5];
  float* out = (float*)d_out;
  char* ws = (char*)d_ws;

  u16* xb  = (u16*)(ws + 0L);
  u16* W1b = (u16*)(ws + 67108864L);
  u16* W2b = (u16*)(ws + 100663296L);
  u16* Lb  = (u16*)(ws + 134217728L);
  u16* Mb  = (u16*)(ws + 138412032L);
  u16* Pt  = (u16*)(ws + 142606336L);
  u16* MPt = (u16*)(ws + 209715200L);
  u16* Sb  = (u16*)(ws + 276824064L);
  u16* Ob  = MPt;  // reuse: MPt consumed by S-gemm before O-gemm writes

  hipFuncSetAttribute((const void*)gemm_nt2<0,false>, hipFuncAttributeMaxDynamicSharedMemorySize, LDSB);
  hipFuncSetAttribute((const void*)gemm_nt2<1,true >, hipFuncAttributeMaxDynamicSharedMemorySize, LDSB);
  hipFuncSetAttribute((const void*)gemm_nt2<2,false>, hipFuncAttributeMaxDynamicSharedMemorySize, LDSB);
  hipFuncSetAttribute((const void*)gemm_nt2<3,true >, hipFuncAttributeMaxDynamicSharedMemorySize, LDSB);

  // preps
  cast_bf16_kernel<<<4096,256,0,stream>>>(x,  xb,  4194304L);
  cast_bf16_kernel<<<4096,256,0,stream>>>(W1, W1b, 2097152L);
  cast_bf16_kernel<<<4096,256,0,stream>>>(W2, W2b, 2097152L);
  mask_cast_L_kernel<<<1024,256,0,stream>>>(pre, Lb);

  // M[n] = L[n] ·NT· L[n]          (8 batches, 512^3)
  gemm_nt2<0,false><<<dim3(2,2,8),512,LDSB,stream>>>(Lb, Lb, Mb, 512, 512,512,512,
      0, 262144, 0, 262144, 0, 262144, nullptr, 0.f);

  // PtG = W1b ·NT· xb + b1[row]    (4096 x 8192, K=4096)
  gemm_nt2<1,true><<<dim3(32,16,1),512,LDSB,stream>>>(W1b, xb, Pt, 4096, 4096,4096,8192,
      0,0, 0,0, 0,0, b1, 0.f);

  // MPt[z] = Pt(b,n) ·NT· M[n]     (128 batches, 512^3)
  gemm_nt2<0,false><<<dim3(2,2,128),512,LDSB,stream>>>(Pt, Mb, MPt, 512, 8192,512,512,
      512, 512L*8192, 0, 262144, 8L*262144, 262144, nullptr, 0.f);

  // S[z] = Pt(b,n) ·NT· MPt[z], then *1/sqrt(512) and tril mask
  gemm_nt2<2,false><<<dim3(2,2,128),512,LDSB,stream>>>(Pt, MPt, Sb, 512, 8192,512,512,
      512, 512L*8192, 8L*262144, 262144, 8L*262144, 262144, nullptr, 0.04419417382f);

  // O(b,n) = S[z] ·NT· Pt(b,n)  -> Ob (8192 x 4096, block at [b*512, n*512])
  gemm_nt2<0,false><<<dim3(2,2,128),512,LDSB,stream>>>(Sb, Pt, Ob, 512, 512,8192,4096,
      8L*262144, 262144, 512, 512L*8192, 512L*4096, 512, nullptr, 0.f);

  // Y = Ob ·NT· W2b + b2[col]      (8192 x 4096, K=4096, fp32 out)
  gemm_nt2<3,true><<<dim3(16,32,1),512,LDSB,stream>>>(Ob, W2b, out, 4096, 4096,4096,4096,
      0,0, 0,0, 0,0, b2, 0.f);
}

// Round 6
// 717.016 us; speedup vs baseline: 4.7762x; 4.7762x over previous
//
#include <hip/hip_runtime.h>
#include <stdint.h>

typedef uint16_t u16;
typedef short short8 __attribute__((ext_vector_type(8)));
typedef float f32x4 __attribute__((ext_vector_type(4)));

__device__ __forceinline__ u16 f2bf(float f){
  uint32_t u = __float_as_uint(f);
  u += 0x7fff + ((u >> 16) & 1);   // RNE
  return (u16)(u >> 16);
}

__device__ __forceinline__ void gload_lds16(const u16* g, const char* l){
  __builtin_amdgcn_global_load_lds((const __attribute__((address_space(1))) void*)g,
                                   (__attribute__((address_space(3))) void*)l,
                                   16, 0, 0);
}

// ---- prep: fp32 -> bf16 cast (vectorized, 8 elems/thread/iter) ----
__global__ void cast_bf16_kernel(const float* __restrict__ src, u16* __restrict__ dst, long n8){
  long i = (long)blockIdx.x * blockDim.x + threadIdx.x;
  long stride = (long)gridDim.x * blockDim.x;
  for (; i < n8; i += stride){
    float4 a = *(const float4*)(src + i*8);
    float4 b = *(const float4*)(src + i*8 + 4);
    u16 r[8] = {f2bf(a.x), f2bf(a.y), f2bf(a.z), f2bf(a.w),
                f2bf(b.x), f2bf(b.y), f2bf(b.z), f2bf(b.w)};
    *(uint4*)(dst + i*8) = *(const uint4*)r;
  }
}

// ---- prep: L = tril(pre) cast to bf16 ; layout (n,u,v) 8x512x512 ----
__global__ void mask_cast_L_kernel(const float* __restrict__ pre, u16* __restrict__ L){
  long i = (long)blockIdx.x * blockDim.x + threadIdx.x;  // chunk of 8 along v
  if (i >= 8L*512*64) return;
  int v0 = (int)(i & 63) * 8;
  int u  = (int)((i >> 6) & 511);
  float4 a = *(const float4*)(pre + i*8);
  float4 b = *(const float4*)(pre + i*8 + 4);
  float vals[8] = {a.x,a.y,a.z,a.w,b.x,b.y,b.z,b.w};
  u16 r[8];
  #pragma unroll
  for (int j=0;j<8;j++) r[j] = f2bf((v0 + j <= u) ? vals[j] : 0.0f);
  *(uint4*)(L + i*8) = *(const uint4*)r;
}

// ---- 8-phase NT GEMM (m201-style): C[M,N] = A(MxK,rm) * B(NxK,rm)^T ----
// 256x256 tile, BK=64, 8 waves (2Mx4N), wave tile 128x64, acc[8][4].
// LDS 128KB = 2 K-tile buffers x 4 half-tiles {A0,A1,B0,B1} x 16KB.
// Half-tile = 128 rows x 64 K-elems, row-major 128B rows, chunk-XOR swizzle:
//   phys_chunk = logical_chunk ^ (row&7)  (16B chunks; 2-way max = free)
// applied on the pre-swizzled GLOBAL source (linear gload_lds dest) and on
// the ds_read address (both-sides involution).
// Per K-tile: 4 phases x {reads pre-barrier -> barrier -> 16 MFMA -> barrier}.
// Reads/phase: {12,4,8,0} (A-quad + B-half reuse). Stages: B(kt+2)@P3,
// A(kt+2)@P4; vmcnt(8) once per K-tile at P4 (2 tiles always in flight).
// EPI: 0 = bf16; 1 = +bias[row] bf16; 2 = tril*scale bf16; 3 = +bias[col] fp32.
template<int EPI, bool SWZ>
__global__ __launch_bounds__(512, 1)
void gemm8p(const u16* __restrict__ A, const u16* __restrict__ B,
            void* __restrict__ Cv, int K, int lda, int ldb, int ldc,
            long asb, long asn, long bsb, long bsn, long csb, long csn,
            const float* __restrict__ bias, float scale)
{
  extern __shared__ __align__(16) char smem[];   // 131072 B
  const int t = threadIdx.x;
  const int lane = t & 63;
  const int wave = t >> 6;          // 0..7
  const int wm = wave >> 2;         // 0..1
  const int wn = wave & 3;          // 0..3
  const long zb = blockIdx.z >> 3, zn = blockIdx.z & 7;
  A += zb*asb + zn*asn;
  B += zb*bsb + zn*bsn;

  int bx = blockIdx.x, by = blockIdx.y;
  if constexpr (SWZ){
    int nbx = gridDim.x;
    int bid = bx + by * nbx;
    int chunk = (nbx * gridDim.y) >> 3;   // blocks per XCD (grid % 8 == 0)
    int b2 = (bid & 7) * chunk + (bid >> 3);
    bx = b2 % nbx;  by = b2 / nbx;
  }
  const int row0 = by * 256, col0 = bx * 256;
  const int l15 = lane & 15, l4 = lane >> 4;

  // LDS read addressing (within a 16KB half-tile, 128B rows):
  const int ca0   = (l4 ^ (l15 & 7)) * 16;        // swizzled 16B chunk, ks=0
  const int aoff0 = l15*128 + ca0;                // + row(l15) byte offset
  const int aoff1 = aoff0 ^ 64;                   // ks=1 chunk = chunk0 ^ 4
  const int aB = wm*16384;                        // my A half-tile (A0/A1)
  const int bB = 32768 + (wn>>1)*16384 + (wn&1)*8192;  // my B half + 64-row sub
  const int stT = t*16;                           // linear staging dest slot

  // staging source: thread t -> (row = t>>3, chunk = t&7), col pre-swizzled
  const int srow = t >> 3;                        // 0..63
  const int scol = ((t & 7) ^ (srow & 7)) * 8;    // elements
  const u16* gA0 = A + (long)(row0 + srow)*lda + scol;
  const u16* gB0 = B + (long)(col0 + srow)*ldb + scol;
  const long a64 = 64L*lda, b64 = 64L*ldb;

  f32x4 acc[8][4];
  #pragma unroll
  for (int m=0;m<8;m++)
    #pragma unroll
    for (int n=0;n<4;n++) acc[m][n] = (f32x4){0.f,0.f,0.f,0.f};

  short8 af[4][2], bf[4][2];
  const int NT = K >> 6;   // K-tiles of 64 (NT even: 8 or 64)

#define STA(D, P) { const u16* p_ = (P); \
  gload_lds16(p_,          smem + (D)*65536 +         stT); \
  gload_lds16(p_ +   a64,  smem + (D)*65536 +  8192 + stT); \
  gload_lds16(p_ + 2*a64,  smem + (D)*65536 + 16384 + stT); \
  gload_lds16(p_ + 3*a64,  smem + (D)*65536 + 24576 + stT); }
#define STB(D, P) { const u16* p_ = (P); \
  gload_lds16(p_,          smem + (D)*65536 + 32768 + stT); \
  gload_lds16(p_ +   b64,  smem + (D)*65536 + 40960 + stT); \
  gload_lds16(p_ + 2*b64,  smem + (D)*65536 + 49152 + stT); \
  gload_lds16(p_ + 3*b64,  smem + (D)*65536 + 57344 + stT); }
#define RDA(D, MB) { _Pragma("unroll") for (int m=0;m<4;m++){ \
  const char* p_ = smem + (D)*65536 + aB + ((MB)+m)*2048; \
  af[m][0] = *(const short8*)(p_ + aoff0); \
  af[m][1] = *(const short8*)(p_ + aoff1); } }
#define RDB(D, NB) { _Pragma("unroll") for (int n=0;n<2;n++){ \
  const char* p_ = smem + (D)*65536 + bB + ((NB)+n)*2048; \
  bf[(NB)+n][0] = *(const short8*)(p_ + aoff0); \
  bf[(NB)+n][1] = *(const short8*)(p_ + aoff1); } }
#define MM(MB, NB) { __builtin_amdgcn_s_setprio(1); \
  _Pragma("unroll") for (int m=0;m<4;m++) \
  _Pragma("unroll") for (int n=0;n<2;n++){ \
    acc[(MB)+m][(NB)+n] = __builtin_amdgcn_mfma_f32_16x16x32_bf16(af[m][0], bf[(NB)+n][0], acc[(MB)+m][(NB)+n],0,0,0); \
    acc[(MB)+m][(NB)+n] = __builtin_amdgcn_mfma_f32_16x16x32_bf16(af[m][1], bf[(NB)+n][1], acc[(MB)+m][(NB)+n],0,0,0); } \
  __builtin_amdgcn_s_setprio(0); }
#define BAR() { asm volatile("" ::: "memory"); __builtin_amdgcn_s_barrier(); asm volatile("" ::: "memory"); }
#define VM(N) asm volatile("s_waitcnt vmcnt(" N ")" ::: "memory");

// One K-tile = 4 phases. Reads precede the mid-barrier (data guaranteed by
// the vmcnt+barrier at P4 of the PREVIOUS tile); MFMA between barriers.
#define TILE(D, DOSTAGE, PA2, PB2, VMS) \
  RDA(D, 0); RDB(D, 0);                  BAR(); MM(0,0); BAR(); \
  RDB(D, 2);                             BAR(); MM(0,2); BAR(); \
  RDA(D, 4); if (DOSTAGE) STB(D, PB2);   BAR(); MM(4,2); BAR(); \
  if (DOSTAGE) STA(D, PA2); VM(VMS);     BAR(); MM(4,0); BAR();

  // prologue: tiles 0 and 1 fully staged; wait tile 0 (8 newest = tile 1)
  STB(0, gB0);      STA(0, gA0);
  STB(1, gB0 + 64); STA(1, gA0 + 64);
  VM("8");
  BAR();

  const u16* sA = gA0 + 128;   // source for tile kt+2 (kt=0 at loop entry)
  const u16* sB = gB0 + 128;
  #pragma unroll 1
  for (int kt2 = 0; kt2 < NT - 2; kt2 += 2){
    TILE(0, true, sA,      sB,      "8")
    TILE(1, true, sA + 64, sB + 64, "8")
    sA += 128; sB += 128;
  }
  // tail: kt = NT-2 (buf 0), NT-1 (buf 1); no stages; exact drains
  TILE(0, false, sA, sB, "0")
  TILE(1, false, sA, sB, "0")

#undef STA
#undef STB
#undef RDA
#undef RDB
#undef MM
#undef BAR
#undef VM
#undef TILE

  // epilogue: C/D map col=lane&15, row=(lane>>4)*4+g  (HW-verified)
  if constexpr (EPI == 3){
    float* C = (float*)Cv;
    #pragma unroll
    for (int m=0;m<8;m++){
      int r0 = row0 + wm*128 + m*16 + l4*4;
      #pragma unroll
      for (int n=0;n<4;n++){
        int c = col0 + wn*64 + n*16 + l15;
        float bc = bias[c];
        #pragma unroll
        for (int g=0; g<4; g++)
          C[(long)(r0+g)*ldc + c] = acc[m][n][g] + bc;
      }
    }
  } else {
    u16* C = (u16*)Cv + zb*csb + zn*csn;
    #pragma unroll
    for (int m=0;m<8;m++){
      int r0 = row0 + wm*128 + m*16 + l4*4;
      #pragma unroll
      for (int n=0;n<4;n++){
        int c = col0 + wn*64 + n*16 + l15;
        #pragma unroll
        for (int g=0;g<4;g++){
          float v = acc[m][n][g];
          int r = r0 + g;
          if constexpr (EPI==1) v += bias[r];
          if constexpr (EPI==2) v = (c <= r) ? v*scale : 0.0f;
          C[(long)r*ldc + c] = f2bf(v);
        }
      }
    }
  }
}

// Workspace layout (bytes):
//   xb   @ 0          : 8192x4096 bf16
//   W1b  @ 67108864   : 4096x4096 bf16
//   W2b  @ 100663296  : 4096x4096 bf16
//   Lb   @ 134217728  : 8x512x512 bf16
//   Mb   @ 138412032  : 8x512x512 bf16
//   PtG  @ 142606336  : 4096x8192 bf16   PtG[c][r] = P_full[r][c]
//   MPt  @ 209715200  : 128x512x512 bf16 MPt[z][j][u] = MP[b,n,u,j]
//   Sb   @ 276824064  : 128x512x512 bf16
//   Ob   = MPt (reuse; MPt dead after S-gemm)

#define LDSB 131072

extern "C" void kernel_launch(void* const* d_in, const int* in_sizes, int n_in,
                              void* d_out, int out_size, void* d_ws, size_t ws_size,
                              hipStream_t stream)
{
  (void)in_sizes; (void)n_in; (void)out_size; (void)ws_size;
  const float* x   = (const float*)d_in[0];
  const float* W1  = (const float*)d_in[1];
  const float* b1  = (const float*)d_in[2];
  const float* pre = (const float*)d_in[3];
  const float* W2  = (const float*)d_in[4];
  const float* b2  = (const float*)d_in[5];
  float* out = (float*)d_out;
  char* ws = (char*)d_ws;

  u16* xb  = (u16*)(ws + 0L);
  u16* W1b = (u16*)(ws + 67108864L);
  u16* W2b = (u16*)(ws + 100663296L);
  u16* Lb  = (u16*)(ws + 134217728L);
  u16* Mb  = (u16*)(ws + 138412032L);
  u16* Pt  = (u16*)(ws + 142606336L);
  u16* MPt = (u16*)(ws + 209715200L);
  u16* Sb  = (u16*)(ws + 276824064L);
  u16* Ob  = MPt;  // reuse: MPt consumed by S-gemm before O-gemm writes

  hipFuncSetAttribute((const void*)gemm8p<0,false>, hipFuncAttributeMaxDynamicSharedMemorySize, LDSB);
  hipFuncSetAttribute((const void*)gemm8p<1,true >, hipFuncAttributeMaxDynamicSharedMemorySize, LDSB);
  hipFuncSetAttribute((const void*)gemm8p<2,false>, hipFuncAttributeMaxDynamicSharedMemorySize, LDSB);
  hipFuncSetAttribute((const void*)gemm8p<3,true >, hipFuncAttributeMaxDynamicSharedMemorySize, LDSB);

  // preps
  cast_bf16_kernel<<<4096,256,0,stream>>>(x,  xb,  4194304L);
  cast_bf16_kernel<<<4096,256,0,stream>>>(W1, W1b, 2097152L);
  cast_bf16_kernel<<<4096,256,0,stream>>>(W2, W2b, 2097152L);
  mask_cast_L_kernel<<<1024,256,0,stream>>>(pre, Lb);

  // M[n] = L[n] ·NT· L[n]          (8 batches, 512^3)
  gemm8p<0,false><<<dim3(2,2,8),512,LDSB,stream>>>(Lb, Lb, Mb, 512, 512,512,512,
      0, 262144, 0, 262144, 0, 262144, nullptr, 0.f);

  // PtG = W1b ·NT· xb + b1[row]    (4096 x 8192, K=4096)
  gemm8p<1,true><<<dim3(32,16,1),512,LDSB,stream>>>(W1b, xb, Pt, 4096, 4096,4096,8192,
      0,0, 0,0, 0,0, b1, 0.f);

  // MPt[z] = Pt(b,n) ·NT· M[n]     (128 batches, 512^3)
  gemm8p<0,false><<<dim3(2,2,128),512,LDSB,stream>>>(Pt, Mb, MPt, 512, 8192,512,512,
      512, 512L*8192, 0, 262144, 8L*262144, 262144, nullptr, 0.f);

  // S[z] = Pt(b,n) ·NT· MPt[z], then *1/sqrt(512) and tril mask
  gemm8p<2,false><<<dim3(2,2,128),512,LDSB,stream>>>(Pt, MPt, Sb, 512, 8192,512,512,
      512, 512L*8192, 8L*262144, 262144, 8L*262144, 262144, nullptr, 0.04419417382f);

  // O(b,n) = S[z] ·NT· Pt(b,n)  -> Ob (8192 x 4096, block at [b*512, n*512])
  gemm8p<0,false><<<dim3(2,2,128),512,LDSB,stream>>>(Sb, Pt, Ob, 512, 512,8192,4096,
      8L*262144, 262144, 512, 512L*8192, 512L*4096, 512, nullptr, 0.f);

  // Y = Ob ·NT· W2b + b2[col]      (8192 x 4096, K=4096, fp32 out)
  gemm8p<3,true><<<dim3(16,32,1),512,LDSB,stream>>>(Ob, W2b, out, 4096, 4096,4096,4096,
      0,0, 0,0, 0,0, b2, 0.f);
}